// Round 1
// baseline (173481.238 us; speedup 1.0000x reference)
//
#include <hip/hip_runtime.h>

// Problem constants
#define T_LEN 2048
#define I_DIM 128
#define H_DIM 256

// Partitioning: 8 groups (2 dir x 4 batch-tiles of 32) x 32 CUs.
// group = wg & 7 (XCD-locality heuristic), cu = wg >> 3.
// Each CU owns hidden indices [cu*8, cu*8+8).

// LDS layout (floats)
#define IN1_STRIDE 388              // [32][128 x | 256 h1] padded
#define IN1_OFF 0                   // 32*388 = 12416
#define H2P_STRIDE 260
#define H2P_OFF 12416               // 32*260 = 8320
#define RED_OFF 20736               // [4][48][33] = 6336
#define GATES_OFF 27072             // [48][33] = 1584
#define LDS_FLOATS 28656            // 114624 bytes

__device__ __forceinline__ float sigmoidf_(float v) { return 1.f / (1.f + __expf(-v)); }

__global__ __launch_bounds__(256, 1)
void brnn_persistent(const float* __restrict__ x,
                     const float* __restrict__ w1x, const float* __restrict__ b1x,
                     const float* __restrict__ w1h, const float* __restrict__ b1h,
                     const float* __restrict__ w2x, const float* __restrict__ b2x,
                     const float* __restrict__ w2h, const float* __restrict__ b2h,
                     int* flags, float* h1g, float* h2g)
{
    extern __shared__ float smem[];
    float* in1   = smem + IN1_OFF;    // [32][388]: cols 0..127 = x_t, 128..383 = h1
    float* h2p   = smem + H2P_OFF;    // [32][260]: previous h2 (full)
    float* red   = smem + RED_OFF;    // [4][48][33] partial sums
    float* gates = smem + GATES_OFF;  // [48][33]

    const int tid = threadIdx.x;
    const int wg  = blockIdx.x;
    const int grp = wg & 7;
    const int cu  = wg >> 3;          // 0..31
    const int dir = grp >> 2;         // 0 fwd, 1 bwd
    const int btile = grp & 3;
    const int b0 = btile * 32;

    // ---------- phase-1 (LSTM) weights in VGPRs ----------
    // thread -> (r1 = row in 32-row slice, cc1 = 48-col chunk of 384)
    const int r1  = tid & 31;
    const int cc1 = tid >> 5;                  // 0..7
    const int g1  = r1 >> 3;                   // gate 0..3 (i,f,g,o)
    const int jj1 = r1 & 7;
    const int R1  = g1 * H_DIM + cu * 8 + jj1; // row in [1024]
    float W1[48];
    #pragma unroll
    for (int k = 0; k < 48; ++k) {
        int c = cc1 * 48 + k;
        W1[k] = (c < I_DIM) ? w1x[R1 * I_DIM + c] : w1h[R1 * H_DIM + (c - I_DIM)];
    }

    // ---------- phase-2 (GRU) weights in VGPRs ----------
    // thread -> (r2 = row 0..63 [48 active: 0..23 = x-proj r,z,n; 24..47 = h-proj], cc2 = 64-col chunk)
    const int r2  = tid & 63;
    const int cc2 = tid >> 6;                  // 0..3
    float W2[64];
    {
        bool act = (r2 < 48);
        int rr = act ? r2 : 0;
        bool isH = rr >= 24;
        int rx = isH ? rr - 24 : rr;
        int g2 = rx >> 3, jj2 = rx & 7;
        int R2 = g2 * H_DIM + cu * 8 + jj2;
        const float* src = isH ? w2h : w2x;
        #pragma unroll
        for (int k = 0; k < 64; ++k) W2[k] = act ? src[R2 * H_DIM + cc2 * 64 + k] : 0.f;
    }

    // ---------- (j,b) state-owner thread constants ----------
    const int jj = tid >> 5;          // 0..7
    const int bb = tid & 31;          // 0..31
    const int jglob = cu * 8 + jj;
    float bias1[4];
    #pragma unroll
    for (int g = 0; g < 4; ++g) bias1[g] = b1x[g * H_DIM + jglob] + b1h[g * H_DIM + jglob];
    float b2xr[3], b2hr[3];
    #pragma unroll
    for (int g = 0; g < 3; ++g) {
        b2xr[g] = b2x[g * H_DIM + jglob];
        b2hr[g] = b2h[g * H_DIM + jglob];
    }

    float c_reg = 0.f, h2_reg = 0.f;

    // zero h1-region of in1 and h2p (initial hidden states)
    for (int i = tid; i < 32 * 256; i += 256) {
        int b = i >> 8, k = i & 255;
        in1[b * IN1_STRIDE + I_DIM + k] = 0.f;
        h2p[b * H2P_STRIDE + k] = 0.f;
    }
    // load x for t=0
    {
        int teff = dir ? (T_LEN - 1) : 0;
        int b = tid >> 3, q = tid & 7;
        const float4* src = (const float4*)&x[(size_t)(b0 + b) * T_LEN * I_DIM + (size_t)teff * I_DIM + q * 16];
        float4* dst = (float4*)&in1[b * IN1_STRIDE + q * 16];
        dst[0] = src[0]; dst[1] = src[1]; dst[2] = src[2]; dst[3] = src[3];
    }
    __syncthreads();

    const int flagBase = grp * 32;
    const size_t hBase = (size_t)grp * 32 * H_DIM;

    for (int t = 0; t < T_LEN; ++t) {
        // ================= PHASE 1: LSTM =================
        for (int bq = 0; bq < 8; ++bq) {
            float a0 = 0.f, a1 = 0.f, a2 = 0.f, a3 = 0.f;
            const float4* s0 = (const float4*)&in1[(bq * 4 + 0) * IN1_STRIDE + cc1 * 48];
            const float4* s1 = (const float4*)&in1[(bq * 4 + 1) * IN1_STRIDE + cc1 * 48];
            const float4* s2 = (const float4*)&in1[(bq * 4 + 2) * IN1_STRIDE + cc1 * 48];
            const float4* s3 = (const float4*)&in1[(bq * 4 + 3) * IN1_STRIDE + cc1 * 48];
            #pragma unroll
            for (int k4 = 0; k4 < 12; ++k4) {
                float4 v0 = s0[k4], v1 = s1[k4], v2 = s2[k4], v3 = s3[k4];
                float w0 = W1[4*k4+0], w1 = W1[4*k4+1], w2 = W1[4*k4+2], w3 = W1[4*k4+3];
                a0 += w0*v0.x + w1*v0.y + w2*v0.z + w3*v0.w;
                a1 += w0*v1.x + w1*v1.y + w2*v1.z + w3*v1.w;
                a2 += w0*v2.x + w1*v2.y + w2*v2.z + w3*v2.w;
                a3 += w0*v3.x + w1*v3.y + w2*v3.z + w3*v3.w;
            }
            a0 += __shfl_xor(a0, 32); a1 += __shfl_xor(a1, 32);
            a2 += __shfl_xor(a2, 32); a3 += __shfl_xor(a3, 32);
            if ((tid & 32) == 0) {
                int wv = tid >> 6;
                float* rr = &red[(wv * 48 + r1) * 33 + bq * 4];
                rr[0] = a0; rr[1] = a1; rr[2] = a2; rr[3] = a3;
            }
        }
        __syncthreads();
        {   // cc-tree sum -> gates[32][33]
            int r = tid & 31, bq2 = tid >> 5;
            #pragma unroll
            for (int q = 0; q < 4; ++q) {
                int b = bq2 * 4 + q;
                float v = red[(0 * 48 + r) * 33 + b] + red[(1 * 48 + r) * 33 + b]
                        + red[(2 * 48 + r) * 33 + b] + red[(3 * 48 + r) * 33 + b];
                gates[r * 33 + b] = v;
            }
        }
        __syncthreads();
        {   // LSTM nonlinearity; thread (jj,bb) owns c[bb][jglob]
            float gi = gates[(0 * 8 + jj) * 33 + bb] + bias1[0];
            float gf = gates[(1 * 8 + jj) * 33 + bb] + bias1[1];
            float gg = gates[(2 * 8 + jj) * 33 + bb] + bias1[2];
            float go = gates[(3 * 8 + jj) * 33 + bb] + bias1[3];
            float ig = sigmoidf_(gi);
            float fg = sigmoidf_(gf);
            float cg = tanhf(gg);
            float og = sigmoidf_(go);
            c_reg = c_reg * fg + ig * cg;
            float h1v = og * tanhf(c_reg);
            h1g[hBase + (size_t)bb * H_DIM + jglob] = h1v;
        }
        __syncthreads();
        if (tid == 0) {
            __threadfence();
            __hip_atomic_store(&flags[flagBase + cu], 2 * t + 1, __ATOMIC_RELEASE, __HIP_MEMORY_SCOPE_AGENT);
        }
        {   // wait for all 32 CUs of group
            int target = 2 * t + 1;
            if (tid < 64) {
                while (true) {
                    int v = (tid < 32)
                        ? __hip_atomic_load(&flags[flagBase + tid], __ATOMIC_ACQUIRE, __HIP_MEMORY_SCOPE_AGENT)
                        : 0x7fffffff;
                    if (__all(v >= target)) break;
                    __builtin_amdgcn_s_sleep(2);
                }
            }
            __syncthreads();
            __threadfence();   // all waves: invalidate caches before reading peers' h1
        }
        {   // reload full h1 into in1 h-region
            int b = tid >> 3, q = tid & 7;
            const float4* src = (const float4*)&h1g[hBase + (size_t)b * H_DIM + q * 32];
            float4* dst = (float4*)&in1[b * IN1_STRIDE + I_DIM + q * 32];
            #pragma unroll
            for (int i = 0; i < 8; ++i) dst[i] = src[i];
        }
        __syncthreads();

        // ================= PHASE 2: GRU =================
        {
            const float* basep = (r2 < 24) ? (in1 + I_DIM) : h2p;
            const int stride = (r2 < 24) ? IN1_STRIDE : H2P_STRIDE;
            for (int bq = 0; bq < 8; ++bq) {
                float a0 = 0.f, a1 = 0.f, a2 = 0.f, a3 = 0.f;
                const float4* s0 = (const float4*)&basep[(bq * 4 + 0) * stride + cc2 * 64];
                const float4* s1 = (const float4*)&basep[(bq * 4 + 1) * stride + cc2 * 64];
                const float4* s2 = (const float4*)&basep[(bq * 4 + 2) * stride + cc2 * 64];
                const float4* s3 = (const float4*)&basep[(bq * 4 + 3) * stride + cc2 * 64];
                #pragma unroll
                for (int k4 = 0; k4 < 16; ++k4) {
                    float4 v0 = s0[k4], v1 = s1[k4], v2 = s2[k4], v3 = s3[k4];
                    float w0 = W2[4*k4+0], w1 = W2[4*k4+1], w2 = W2[4*k4+2], w3 = W2[4*k4+3];
                    a0 += w0*v0.x + w1*v0.y + w2*v0.z + w3*v0.w;
                    a1 += w0*v1.x + w1*v1.y + w2*v1.z + w3*v1.w;
                    a2 += w0*v2.x + w1*v2.y + w2*v2.z + w3*v2.w;
                    a3 += w0*v3.x + w1*v3.y + w2*v3.z + w3*v3.w;
                }
                if (r2 < 48) {
                    float* rr = &red[(cc2 * 48 + r2) * 33 + bq * 4];
                    rr[0] = a0; rr[1] = a1; rr[2] = a2; rr[3] = a3;
                }
            }
        }
        __syncthreads();
        {   // cc-tree sum -> gates[48][33]
            int rr = tid & 63, bq2 = tid >> 6;
            if (rr < 48) {
                #pragma unroll
                for (int q = 0; q < 8; ++q) {
                    int b = bq2 * 8 + q;
                    float v = red[(0 * 48 + rr) * 33 + b] + red[(1 * 48 + rr) * 33 + b]
                            + red[(2 * 48 + rr) * 33 + b] + red[(3 * 48 + rr) * 33 + b];
                    gates[rr * 33 + b] = v;
                }
            }
        }
        __syncthreads();
        {   // GRU nonlinearity; thread (jj,bb) owns h2[bb][jglob]
            float xr = gates[(0 * 8 + jj) * 33 + bb] + b2xr[0];
            float xz = gates[(1 * 8 + jj) * 33 + bb] + b2xr[1];
            float xn = gates[(2 * 8 + jj) * 33 + bb] + b2xr[2];
            float hr = gates[(24 + 0 * 8 + jj) * 33 + bb] + b2hr[0];
            float hz = gates[(24 + 8 + jj) * 33 + bb] + b2hr[1];
            float hn = gates[(24 + 16 + jj) * 33 + bb] + b2hr[2];
            float rg = sigmoidf_(xr + hr);
            float zg = sigmoidf_(xz + hz);
            float ng = tanhf(xn + rg * hn);
            h2_reg = zg * h2_reg + (1.f - zg) * ng;
            h2g[hBase + (size_t)bb * H_DIM + jglob] = h2_reg;
        }
        __syncthreads();
        if (tid == 0) {
            __threadfence();
            __hip_atomic_store(&flags[flagBase + cu], 2 * t + 2, __ATOMIC_RELEASE, __HIP_MEMORY_SCOPE_AGENT);
        }
        // prefetch next x while waiting (x-region of in1 is idle now)
        if (t + 1 < T_LEN) {
            int teff = dir ? (T_LEN - 2 - t) : (t + 1);
            int b = tid >> 3, q = tid & 7;
            const float4* src = (const float4*)&x[(size_t)(b0 + b) * T_LEN * I_DIM + (size_t)teff * I_DIM + q * 16];
            float4* dst = (float4*)&in1[b * IN1_STRIDE + q * 16];
            dst[0] = src[0]; dst[1] = src[1]; dst[2] = src[2]; dst[3] = src[3];
        }
        {
            int target = 2 * t + 2;
            if (tid < 64) {
                while (true) {
                    int v = (tid < 32)
                        ? __hip_atomic_load(&flags[flagBase + tid], __ATOMIC_ACQUIRE, __HIP_MEMORY_SCOPE_AGENT)
                        : 0x7fffffff;
                    if (__all(v >= target)) break;
                    __builtin_amdgcn_s_sleep(2);
                }
            }
            __syncthreads();
            __threadfence();
        }
        {   // reload full h2 into h2p
            int b = tid >> 3, q = tid & 7;
            const float4* src = (const float4*)&h2g[hBase + (size_t)b * H_DIM + q * 32];
            float4* dst = (float4*)&h2p[b * H2P_STRIDE + q * 32];
            #pragma unroll
            for (int i = 0; i < 8; ++i) dst[i] = src[i];
        }
        __syncthreads();
    }
}

// out[b][o] = concat(h_fwd[b], h_bwd[b]) . wo[o] + bo[o]
__global__ __launch_bounds__(128)
void brnn_out(const float* __restrict__ h2g, const float* __restrict__ wo,
              const float* __restrict__ bo, float* __restrict__ out)
{
    __shared__ float hc[512];
    int b = blockIdx.x;          // 0..127
    int o = threadIdx.x;         // 0..127
    int btile = b >> 5, bi = b & 31;
    for (int k = threadIdx.x; k < 256; k += 128) {
        hc[k]       = h2g[((size_t)(btile)     * 32 + bi) * H_DIM + k];  // fwd: grp = btile
        hc[256 + k] = h2g[((size_t)(4 + btile) * 32 + bi) * H_DIM + k];  // bwd: grp = 4+btile
    }
    __syncthreads();
    float acc = bo[o];
    const float4* w4 = (const float4*)&wo[(size_t)o * 512];
    #pragma unroll 8
    for (int k = 0; k < 128; ++k) {
        float4 w = w4[k];
        acc += w.x * hc[k * 4] + w.y * hc[k * 4 + 1] + w.z * hc[k * 4 + 2] + w.w * hc[k * 4 + 3];
    }
    out[b * 128 + o] = acc;
}

extern "C" void kernel_launch(void* const* d_in, const int* in_sizes, int n_in,
                              void* d_out, int out_size, void* d_ws, size_t ws_size,
                              hipStream_t stream) {
    const float* x   = (const float*)d_in[0];
    const float* w1x = (const float*)d_in[1];
    const float* b1x = (const float*)d_in[2];
    const float* w1h = (const float*)d_in[3];
    const float* b1h = (const float*)d_in[4];
    const float* w2x = (const float*)d_in[5];
    const float* b2x = (const float*)d_in[6];
    const float* w2h = (const float*)d_in[7];
    const float* b2h = (const float*)d_in[8];
    const float* wo  = (const float*)d_in[9];
    const float* bo  = (const float*)d_in[10];
    float* out = (float*)d_out;

    char* ws = (char*)d_ws;
    int*   flags = (int*)ws;                           // 8*32 ints
    float* h1g   = (float*)(ws + 4096);                // 8*32*256 floats = 256KB
    float* h2g   = (float*)(ws + 4096 + 8 * 32 * 256 * 4);

    hipMemsetAsync(flags, 0, 8 * 32 * sizeof(int), stream);

    size_t shmem = LDS_FLOATS * sizeof(float);
    hipFuncSetAttribute((const void*)brnn_persistent,
                        hipFuncAttributeMaxDynamicSharedMemorySize, (int)shmem);

    void* args[] = { (void*)&x, (void*)&w1x, (void*)&b1x, (void*)&w1h, (void*)&b1h,
                     (void*)&w2x, (void*)&b2x, (void*)&w2h, (void*)&b2h,
                     (void*)&flags, (void*)&h1g, (void*)&h2g };
    hipError_t err = hipLaunchCooperativeKernel((void*)brnn_persistent,
                                                dim3(256), dim3(256), args,
                                                (unsigned int)shmem, stream);
    if (err != hipSuccess) {
        // fall back to a plain launch: 256 blocks at 1 block/CU (LDS-limited) on a
        // 256-CU idle device -> all blocks co-resident.
        brnn_persistent<<<dim3(256), dim3(256), shmem, stream>>>(
            x, w1x, b1x, w1h, b1h, w2x, b2x, w2h, b2h, flags, h1g, h2g);
    }

    brnn_out<<<dim3(128), dim3(128), 0, stream>>>(h2g, wo, bo, out);
}

// Round 2
// 62385.803 us; speedup vs baseline: 2.7808x; 2.7808x over previous
//
#include <hip/hip_runtime.h>

// Problem constants
#define T_LEN 2048
#define I_DIM 128
#define H_DIM 256

// Partitioning: 8 groups (2 dir x 4 batch-tiles of 32) x 32 CUs.
// group = wg & 7 (XCD-locality heuristic), cu = wg >> 3.
// Each CU owns hidden indices [cu*8, cu*8+8).
//
// Super-step s (0..T): computes LSTM(s) [s<T] and GRU(s-1) [s>=1], then ONE
// group barrier exchanging h1(s) and h2(s-1) via cache-bypassing relaxed
// agent-scope atomics (no threadfence anywhere in the loop).

// LDS layout (floats)
#define IN1_STRIDE 388              // [32][128 x | 256 h1]
#define IN1_OFF 0                   // 12416
#define H2P_STRIDE 260
#define H2P_OFF 12416               // 8320
#define REDL_OFF 20736              // [4][32][33] = 4224
#define REDG_OFF 24960              // [4][48][33] = 6336
#define GATESL_OFF 31296            // [32][33] = 1056
#define GATESG_OFF 32352            // [48][33] = 1584
#define HSTG1_OFF 33936             // 256
#define HSTG2_OFF 34192             // 256
#define LDS_FLOATS 34448            // 137792 bytes

__device__ __forceinline__ float sigmoidf_(float v) { return 1.f / (1.f + __expf(-v)); }

__global__ __launch_bounds__(256, 1)
void brnn_persistent(const float* __restrict__ x,
                     const float* __restrict__ w1x, const float* __restrict__ b1x,
                     const float* __restrict__ w1h, const float* __restrict__ b1h,
                     const float* __restrict__ w2x, const float* __restrict__ b2x,
                     const float* __restrict__ w2h, const float* __restrict__ b2h,
                     int* flags, unsigned long long* hxg, float* h2out)
{
    extern __shared__ float smem[];
    float* in1     = smem + IN1_OFF;    // [32][388]: 0..127 = x_t, 128..383 = h1(s-1)
    float* h2p     = smem + H2P_OFF;    // [32][260]: h2(s-2)
    float* redL    = smem + REDL_OFF;
    float* redG    = smem + REDG_OFF;
    float* gatesL  = smem + GATESL_OFF;
    float* gatesG  = smem + GATESG_OFF;
    float* hstage1 = smem + HSTG1_OFF;  // [32 b][8 j] = h1(s) slice
    float* hstage2 = smem + HSTG2_OFF;  // [32 b][8 j] = h2(s-1) slice

    const int tid = threadIdx.x;
    const int wg  = blockIdx.x;
    const int grp = wg & 7;
    const int cu  = wg >> 3;          // 0..31
    const int dir = grp >> 2;
    const int btile = grp & 3;
    const int b0 = btile * 32;

    // ---------- LSTM weights in VGPRs: thread = (row r1 of 32, chunk cc1 of 8x48) ----------
    const int r1  = tid & 31;
    const int cc1 = tid >> 5;                  // 0..7
    const int g1  = r1 >> 3;
    const int jj1 = r1 & 7;
    const int R1  = g1 * H_DIM + cu * 8 + jj1;
    float W1[48];
    #pragma unroll
    for (int k = 0; k < 48; ++k) {
        int c = cc1 * 48 + k;
        W1[k] = (c < I_DIM) ? w1x[R1 * I_DIM + c] : w1h[R1 * H_DIM + (c - I_DIM)];
    }

    // ---------- GRU weights in VGPRs: thread = (row r2 of 64 [48 active], chunk cc2 of 4x64) ----------
    const int r2  = tid & 63;
    const int cc2 = tid >> 6;                  // 0..3 (= wave id)
    float W2[64];
    {
        bool act = (r2 < 48);
        int rr = act ? r2 : 0;
        bool isH = rr >= 24;
        int rx = isH ? rr - 24 : rr;
        int g2 = rx >> 3, jj2 = rx & 7;
        int R2 = g2 * H_DIM + cu * 8 + jj2;
        const float* src = isH ? w2h : w2x;
        #pragma unroll
        for (int k = 0; k < 64; ++k) W2[k] = act ? src[R2 * H_DIM + cc2 * 64 + k] : 0.f;
    }
    const float* gbase = (r2 < 24) ? (in1 + I_DIM) : h2p;   // GRU dot input base
    const int    gstr  = (r2 < 24) ? IN1_STRIDE : H2P_STRIDE;

    // ---------- (j,b) state-owner thread constants ----------
    const int jj = tid >> 5;          // 0..7
    const int bb = tid & 31;          // 0..31
    const int jglob = cu * 8 + jj;
    float bias1[4];
    #pragma unroll
    for (int g = 0; g < 4; ++g) bias1[g] = b1x[g * H_DIM + jglob] + b1h[g * H_DIM + jglob];
    float b2xr[3], b2hr[3];
    #pragma unroll
    for (int g = 0; g < 3; ++g) {
        b2xr[g] = b2x[g * H_DIM + jglob];
        b2hr[g] = b2h[g * H_DIM + jglob];
    }

    float c_reg = 0.f, h2_reg = 0.f;

    // zero h1-region of in1, h2p, hstage2 (h2(-1) = 0)
    for (int i = tid; i < 32 * 256; i += 256) {
        int b = i >> 8, k = i & 255;
        in1[b * IN1_STRIDE + I_DIM + k] = 0.f;
        h2p[b * H2P_STRIDE + k] = 0.f;
    }
    hstage2[tid] = 0.f;
    // load x(0)
    {
        int teff = dir ? (T_LEN - 1) : 0;
        int b = tid >> 3, q = tid & 7;
        const float4* src = (const float4*)&x[(size_t)(b0 + b) * T_LEN * I_DIM + (size_t)teff * I_DIM + q * 16];
        float4* dst = (float4*)&in1[b * IN1_STRIDE + q * 16];
        dst[0] = src[0]; dst[1] = src[1]; dst[2] = src[2]; dst[3] = src[3];
    }
    __syncthreads();

    const int flagBase = grp * 32;

    for (int s = 0; s <= T_LEN; ++s) {
        // ---------- LSTM(s) dots ----------
        if (s < T_LEN) {
            for (int bq = 0; bq < 8; ++bq) {
                float a0 = 0.f, a1 = 0.f, a2 = 0.f, a3 = 0.f;
                const float4* s0 = (const float4*)&in1[(bq * 4 + 0) * IN1_STRIDE + cc1 * 48];
                const float4* s1 = (const float4*)&in1[(bq * 4 + 1) * IN1_STRIDE + cc1 * 48];
                const float4* s2 = (const float4*)&in1[(bq * 4 + 2) * IN1_STRIDE + cc1 * 48];
                const float4* s3 = (const float4*)&in1[(bq * 4 + 3) * IN1_STRIDE + cc1 * 48];
                #pragma unroll
                for (int k4 = 0; k4 < 12; ++k4) {
                    float4 v0 = s0[k4], v1 = s1[k4], v2 = s2[k4], v3 = s3[k4];
                    float w0 = W1[4*k4+0], w1 = W1[4*k4+1], w2 = W1[4*k4+2], w3 = W1[4*k4+3];
                    a0 += w0*v0.x + w1*v0.y + w2*v0.z + w3*v0.w;
                    a1 += w0*v1.x + w1*v1.y + w2*v1.z + w3*v1.w;
                    a2 += w0*v2.x + w1*v2.y + w2*v2.z + w3*v2.w;
                    a3 += w0*v3.x + w1*v3.y + w2*v3.z + w3*v3.w;
                }
                a0 += __shfl_xor(a0, 32); a1 += __shfl_xor(a1, 32);
                a2 += __shfl_xor(a2, 32); a3 += __shfl_xor(a3, 32);
                if ((tid & 32) == 0) {
                    int wv = tid >> 6;
                    float* rr = &redL[(wv * 32 + r1) * 33 + bq * 4];
                    rr[0] = a0; rr[1] = a1; rr[2] = a2; rr[3] = a3;
                }
            }
        }
        // ---------- GRU(s-1) dots (inputs: h1(s-1) in in1-h, h2(s-2) in h2p) ----------
        if (s >= 1) {
            for (int bq = 0; bq < 8; ++bq) {
                float a0 = 0.f, a1 = 0.f, a2 = 0.f, a3 = 0.f;
                const float4* s0 = (const float4*)&gbase[(bq * 4 + 0) * gstr + cc2 * 64];
                const float4* s1 = (const float4*)&gbase[(bq * 4 + 1) * gstr + cc2 * 64];
                const float4* s2 = (const float4*)&gbase[(bq * 4 + 2) * gstr + cc2 * 64];
                const float4* s3 = (const float4*)&gbase[(bq * 4 + 3) * gstr + cc2 * 64];
                #pragma unroll
                for (int k4 = 0; k4 < 16; ++k4) {
                    float4 v0 = s0[k4], v1 = s1[k4], v2 = s2[k4], v3 = s3[k4];
                    float w0 = W2[4*k4+0], w1 = W2[4*k4+1], w2 = W2[4*k4+2], w3 = W2[4*k4+3];
                    a0 += w0*v0.x + w1*v0.y + w2*v0.z + w3*v0.w;
                    a1 += w0*v1.x + w1*v1.y + w2*v1.z + w3*v1.w;
                    a2 += w0*v2.x + w1*v2.y + w2*v2.z + w3*v2.w;
                    a3 += w0*v3.x + w1*v3.y + w2*v3.z + w3*v3.w;
                }
                if (r2 < 48) {
                    float* rr = &redG[(cc2 * 48 + r2) * 33 + bq * 4];
                    rr[0] = a0; rr[1] = a1; rr[2] = a2; rr[3] = a3;
                }
            }
        }
        __syncthreads();
        // ---------- tree sums ----------
        if (s < T_LEN) {
            int r = tid & 31, bq2 = tid >> 5;
            #pragma unroll
            for (int q = 0; q < 4; ++q) {
                int b = bq2 * 4 + q;
                gatesL[r * 33 + b] = redL[(0 * 32 + r) * 33 + b] + redL[(1 * 32 + r) * 33 + b]
                                   + redL[(2 * 32 + r) * 33 + b] + redL[(3 * 32 + r) * 33 + b];
            }
        }
        if (s >= 1) {
            int rr = tid & 63, bq2 = tid >> 6;
            if (rr < 48) {
                #pragma unroll
                for (int q = 0; q < 8; ++q) {
                    int b = bq2 * 8 + q;
                    gatesG[rr * 33 + b] = redG[(0 * 48 + rr) * 33 + b] + redG[(1 * 48 + rr) * 33 + b]
                                        + redG[(2 * 48 + rr) * 33 + b] + redG[(3 * 48 + rr) * 33 + b];
                }
            }
        }
        __syncthreads();
        // ---------- nonlinearities (thread (jj,bb)) ----------
        if (s < T_LEN) {
            float gi = gatesL[(0 * 8 + jj) * 33 + bb] + bias1[0];
            float gf = gatesL[(1 * 8 + jj) * 33 + bb] + bias1[1];
            float gg = gatesL[(2 * 8 + jj) * 33 + bb] + bias1[2];
            float go = gatesL[(3 * 8 + jj) * 33 + bb] + bias1[3];
            float ig = sigmoidf_(gi);
            float fg = sigmoidf_(gf);
            float cg = tanhf(gg);
            float og = sigmoidf_(go);
            c_reg = c_reg * fg + ig * cg;
            hstage1[bb * 8 + jj] = og * tanhf(c_reg);
        }
        if (s >= 1) {
            float xr = gatesG[(0 * 8 + jj) * 33 + bb] + b2xr[0];
            float xz = gatesG[(1 * 8 + jj) * 33 + bb] + b2xr[1];
            float xn = gatesG[(2 * 8 + jj) * 33 + bb] + b2xr[2];
            float hr = gatesG[(24 + 0 * 8 + jj) * 33 + bb] + b2hr[0];
            float hz = gatesG[(24 + 8 + jj) * 33 + bb] + b2hr[1];
            float hn = gatesG[(24 + 16 + jj) * 33 + bb] + b2hr[2];
            float rg = sigmoidf_(xr + hr);
            float zg = sigmoidf_(xz + hz);
            float ng = tanhf(xn + rg * hn);
            h2_reg = zg * h2_reg + (1.f - zg) * ng;
            hstage2[bb * 8 + jj] = h2_reg;
            if (s == T_LEN)   // final: h2(T-1)
                h2out[((size_t)(grp * 32 + bb)) * H_DIM + jglob] = h2_reg;
        }
        __syncthreads();

        if (s == T_LEN) break;

        // ---------- exchange: cache-bypassing stores from LDS stage ----------
        {
            unsigned long long v;
            if (tid < 128) v = *(const unsigned long long*)&hstage1[2 * tid];
            else           v = *(const unsigned long long*)&hstage2[2 * (tid - 128)];
            unsigned long long* dst = hxg + (size_t)(s & 1) * 65536 + (size_t)grp * 8192
                                          + (size_t)cu * 256 + tid;
            __hip_atomic_store(dst, v, __ATOMIC_RELAXED, __HIP_MEMORY_SCOPE_AGENT);
        }
        __syncthreads();   // drains vmcnt of every wave's stores before the flag
        if (tid == 0)
            __hip_atomic_store(&flags[(flagBase + cu) * 32], s + 1,
                               __ATOMIC_RELAXED, __HIP_MEMORY_SCOPE_AGENT);
        // prefetch x(s+1) while waiting (x-region of in1 idle now)
        if (s + 1 < T_LEN) {
            int teff = dir ? (T_LEN - 2 - s) : (s + 1);
            int b = tid >> 3, q = tid & 7;
            const float4* src = (const float4*)&x[(size_t)(b0 + b) * T_LEN * I_DIM + (size_t)teff * I_DIM + q * 16];
            float4* dst = (float4*)&in1[b * IN1_STRIDE + q * 16];
            dst[0] = src[0]; dst[1] = src[1]; dst[2] = src[2]; dst[3] = src[3];
        }
        // ---------- wait on padded per-CU flags ----------
        {
            int target = s + 1;
            if (tid < 64) {
                while (true) {
                    int v = (tid < 32)
                        ? __hip_atomic_load(&flags[(flagBase + tid) * 32], __ATOMIC_RELAXED, __HIP_MEMORY_SCOPE_AGENT)
                        : 0x7fffffff;
                    if (__all(v >= target)) break;
                    __builtin_amdgcn_s_sleep(1);
                }
            }
            __syncthreads();
        }
        // ---------- reload h1(s) -> in1-h, h2(s-1) -> h2p ----------
        {
            const unsigned long long* src = hxg + (size_t)(s & 1) * 65536 + (size_t)grp * 8192;
            #pragma unroll 16
            for (int i = 0; i < 32; ++i) {
                int flat = tid + 256 * i;
                unsigned long long v = __hip_atomic_load(&src[flat], __ATOMIC_RELAXED, __HIP_MEMORY_SCOPE_AGENT);
                int cu2 = flat >> 8, r = flat & 255;
                int hr = r & 127, b = hr >> 2, jp = hr & 3;
                float* dstl = (r < 128) ? &in1[b * IN1_STRIDE + I_DIM + cu2 * 8 + 2 * jp]
                                        : &h2p[b * H2P_STRIDE + cu2 * 8 + 2 * jp];
                *reinterpret_cast<unsigned long long*>(dstl) = v;
            }
        }
        __syncthreads();
    }
}

// out[b][o] = concat(h_fwd[b], h_bwd[b]) . wo[o] + bo[o]
__global__ __launch_bounds__(128)
void brnn_out(const float* __restrict__ h2out, const float* __restrict__ wo,
              const float* __restrict__ bo, float* __restrict__ out)
{
    __shared__ float hc[512];
    int b = blockIdx.x;
    int o = threadIdx.x;
    int btile = b >> 5, bi = b & 31;
    for (int k = threadIdx.x; k < 256; k += 128) {
        hc[k]       = h2out[((size_t)(btile)     * 32 + bi) * H_DIM + k];
        hc[256 + k] = h2out[((size_t)(4 + btile) * 32 + bi) * H_DIM + k];
    }
    __syncthreads();
    float acc = bo[o];
    const float4* w4 = (const float4*)&wo[(size_t)o * 512];
    #pragma unroll 8
    for (int k = 0; k < 128; ++k) {
        float4 w = w4[k];
        acc += w.x * hc[k * 4] + w.y * hc[k * 4 + 1] + w.z * hc[k * 4 + 2] + w.w * hc[k * 4 + 3];
    }
    out[b * 128 + o] = acc;
}

extern "C" void kernel_launch(void* const* d_in, const int* in_sizes, int n_in,
                              void* d_out, int out_size, void* d_ws, size_t ws_size,
                              hipStream_t stream) {
    const float* x   = (const float*)d_in[0];
    const float* w1x = (const float*)d_in[1];
    const float* b1x = (const float*)d_in[2];
    const float* w1h = (const float*)d_in[3];
    const float* b1h = (const float*)d_in[4];
    const float* w2x = (const float*)d_in[5];
    const float* b2x = (const float*)d_in[6];
    const float* w2h = (const float*)d_in[7];
    const float* b2h = (const float*)d_in[8];
    const float* wo  = (const float*)d_in[9];
    const float* bo  = (const float*)d_in[10];
    float* out = (float*)d_out;

    char* ws = (char*)d_ws;
    int* flags = (int*)ws;                                   // 8*32 padded flags: 32KB
    unsigned long long* hxg = (unsigned long long*)(ws + 32768);   // 2 x 8 x 8192 u64 = 1MB
    float* h2out = (float*)(ws + 32768 + 1048576);           // 256 x 256 floats = 256KB

    hipMemsetAsync(flags, 0, 8 * 32 * 32 * sizeof(int), stream);

    size_t shmem = LDS_FLOATS * sizeof(float);
    hipFuncSetAttribute((const void*)brnn_persistent,
                        hipFuncAttributeMaxDynamicSharedMemorySize, (int)shmem);

    void* args[] = { (void*)&x, (void*)&w1x, (void*)&b1x, (void*)&w1h, (void*)&b1h,
                     (void*)&w2x, (void*)&b2x, (void*)&w2h, (void*)&b2h,
                     (void*)&flags, (void*)&hxg, (void*)&h2out };
    hipError_t err = hipLaunchCooperativeKernel((void*)brnn_persistent,
                                                dim3(256), dim3(256), args,
                                                (unsigned int)shmem, stream);
    if (err != hipSuccess) {
        brnn_persistent<<<dim3(256), dim3(256), shmem, stream>>>(
            x, w1x, b1x, w1h, b1h, w2x, b2x, w2h, b2h, flags, hxg, h2out);
    }

    brnn_out<<<dim3(128), dim3(128), 0, stream>>>(h2out, wo, bo, out);
}

// Round 3
// 21791.823 us; speedup vs baseline: 7.9608x; 2.8628x over previous
//
#include <hip/hip_runtime.h>

// Problem constants
#define T_LEN 2048
#define I_DIM 128
#define H_DIM 256

// Partitioning: 8 groups (2 dir x 4 batch-tiles of 32) x 32 CUs.
// group = wg & 7, cu = wg >> 3. Each CU owns hidden cols [cu*8, cu*8+8).
//
// Per super-step s: LSTM(s) [s<T] and GRU(s-1) [s>=1] as two bf16-split MFMA
// GEMMs (M=32 batch, N=32 rows, K=384/512), then ONE group barrier exchanging
// h1(s), h2(s-1) as bf16 hi/lo in the A-staging layout (linear reload).
//
// A-staging LDS layout (per plane hi/lo): [40 kslice][2 kgrp][32 m][8 e] bf16
//   kslice = k/16 over concat-K [x(128) | h1(256) | h2p(256)] = 640 = 40 slices
//   A-frag for mfma_32x32x16: lane reads 16B at  ks*1024 + lane*16  (linear).
// LDS byte offsets:
#define AHI_OFF 0               // 40960
#define ALO_OFF 40960           // 40960
#define CRED_OFF 81920          // 4 x [32][33] f32 = 16896
#define HSTG_OFF 98816          // 4 x 512B (h1hi,h1lo,h2hi,h2lo) = 2048
#define LDS_BYTES 100864

typedef __attribute__((ext_vector_type(8))) short short8;
typedef __attribute__((ext_vector_type(16))) float f32x16;

__device__ __forceinline__ float sigmoidf_(float v) { return 1.f / (1.f + __expf(-v)); }
__device__ __forceinline__ float tanhf_fast(float v) {
    float t = __expf(-2.f * fabsf(v));
    float r = (1.f - t) / (1.f + t);
    return v < 0.f ? -r : r;
}
__device__ __forceinline__ unsigned short bf16_rne(float f) {
    unsigned u = __float_as_uint(f);
    return (unsigned short)((u + 0x7fffu + ((u >> 16) & 1u)) >> 16);
}
__device__ __forceinline__ void split2(float a, unsigned short& h, unsigned short& l) {
    h = bf16_rne(a);
    float hf = __uint_as_float(((unsigned)h) << 16);
    l = bf16_rne(a - hf);
}

__device__ __forceinline__ void stage_x_fn(const float* __restrict__ x, char* smem_b,
                                           int b0, int teff, int tid) {
    int b = tid >> 3, cq = tid & 7;   // b 0..31, cq = kslice 0..7
    const float4* src = (const float4*)(x + ((size_t)(b0 + b) * T_LEN + teff) * I_DIM + cq * 16);
    float4 v0 = src[0], v1 = src[1], v2 = src[2], v3 = src[3];
    float f[16] = {v0.x, v0.y, v0.z, v0.w, v1.x, v1.y, v1.z, v1.w,
                   v2.x, v2.y, v2.z, v2.w, v3.x, v3.y, v3.z, v3.w};
    short8 H0, H1, L0, L1;
    #pragma unroll
    for (int e = 0; e < 8; ++e) {
        unsigned short h, l;
        split2(f[e], h, l);      H0[e] = (short)h; L0[e] = (short)l;
        split2(f[8 + e], h, l);  H1[e] = (short)h; L1[e] = (short)l;
    }
    char* base = smem_b + cq * 1024 + b * 16;
    *(short8*)(base + AHI_OFF)       = H0;
    *(short8*)(base + AHI_OFF + 512) = H1;
    *(short8*)(base + ALO_OFF)       = L0;
    *(short8*)(base + ALO_OFF + 512) = L1;
}

__global__ __launch_bounds__(256, 1)
void brnn_persistent(const float* __restrict__ x,
                     const float* __restrict__ w1x, const float* __restrict__ b1x,
                     const float* __restrict__ w1h, const float* __restrict__ b1h,
                     const float* __restrict__ w2x, const float* __restrict__ b2x,
                     const float* __restrict__ w2h, const float* __restrict__ b2h,
                     int* flags, unsigned long long* hxg, float* h2out)
{
    extern __shared__ char smem_b[];

    const int tid  = threadIdx.x;
    const int lane = tid & 63;
    const int wid  = tid >> 6;         // wave 0..3
    const int wg   = blockIdx.x;
    const int grp  = wg & 7;
    const int cu   = wg >> 3;          // 0..31
    const int dir  = grp >> 2;
    const int btile = grp & 3;
    const int b0   = btile * 32;

    // ---------------- B-fragment preload (weights -> VGPRs, bf16 hi/lo) ------
    // wave0: LSTM kslices 0..11 (K 0..191: x + h1[0:64))
    // wave1: LSTM kslices 12..23 (K 192..383: h1[64:256))
    // wave2: GRU  kslices 8..23  (kk 0..255 = h1; rows: r=w2x_r, z=w2x_z, xn=w2x_n, hn=0)
    // wave3: GRU  kslices 24..39 (kk 256..511 = h2p; rows: r=w2h_r, z=w2h_z, xn=0, hn=w2h_n)
    const int nrow = lane & 31;        // output row n
    const int jrow = nrow >> 2;        // j within CU slice
    const int q    = nrow & 3;         // gate index
    const int half = lane >> 5;        // k-half of slice
    short8 BH[16], BL[16];
    {
        #pragma unroll
        for (int i = 0; i < 16; ++i) {
            short8 H, L;
            #pragma unroll
            for (int e = 0; e < 8; ++e) {
                int kk = i * 16 + half * 8 + e;
                float v = 0.f;
                if (wid == 0) {
                    if (i < 12) {
                        int k = kk;
                        int R = q * H_DIM + cu * 8 + jrow;
                        v = (k < I_DIM) ? w1x[R * I_DIM + k] : w1h[R * H_DIM + (k - I_DIM)];
                    }
                } else if (wid == 1) {
                    if (i < 12) {
                        int k = 192 + kk;
                        int R = q * H_DIM + cu * 8 + jrow;
                        v = w1h[R * H_DIM + (k - I_DIM)];
                    }
                } else if (wid == 2) {
                    if (q < 3) v = w2x[(q * H_DIM + cu * 8 + jrow) * H_DIM + kk];
                } else {
                    if (q == 0)      v = w2h[(0 * H_DIM + cu * 8 + jrow) * H_DIM + kk];
                    else if (q == 1) v = w2h[(1 * H_DIM + cu * 8 + jrow) * H_DIM + kk];
                    else if (q == 3) v = w2h[(2 * H_DIM + cu * 8 + jrow) * H_DIM + kk];
                }
                unsigned short hh, ll;
                split2(v, hh, ll);
                H[e] = (short)hh; L[e] = (short)ll;
            }
            BH[i] = H; BL[i] = L;
        }
    }

    // ---------------- per-thread state-owner constants -----------------------
    const int bb = tid & 31;           // batch within tile
    const int jj = tid >> 5;           // j within CU slice (0..7)
    const int jglob = cu * 8 + jj;
    const float bi_ = b1x[0 * H_DIM + jglob] + b1h[0 * H_DIM + jglob];
    const float bf_ = b1x[1 * H_DIM + jglob] + b1h[1 * H_DIM + jglob];
    const float bg_ = b1x[2 * H_DIM + jglob] + b1h[2 * H_DIM + jglob];
    const float bo_ = b1x[3 * H_DIM + jglob] + b1h[3 * H_DIM + jglob];
    const float brz_r = b2x[0 * H_DIM + jglob] + b2h[0 * H_DIM + jglob];
    const float brz_z = b2x[1 * H_DIM + jglob] + b2h[1 * H_DIM + jglob];
    const float bnx_  = b2x[2 * H_DIM + jglob];
    const float bnh_  = b2h[2 * H_DIM + jglob];

    float c_reg = 0.f, h2_reg = 0.f;

    // ---------------- init: zero h-history slices 8..39, zero h2 stage -------
    #pragma unroll 8
    for (int i = 0; i < 32; ++i) {
        int f = i * 256 + tid;
        char* dstb = smem_b + ((f >> 12) ? ALO_OFF : AHI_OFF) + 8192 + (size_t)(f & 4095) * 8;
        *(unsigned long long*)dstb = 0ull;
    }
    if (tid < 128) *(unsigned long long*)(smem_b + HSTG_OFF + 1024 + tid * 8) = 0ull;
    stage_x_fn(x, smem_b, b0, dir ? (T_LEN - 1) : 0, tid);
    __syncthreads();

    const int flagBase = grp * 32;

    for (int s = 0; s <= T_LEN; ++s) {
        // ================= MFMA phase =================
        f32x16 accA, accB;
        #pragma unroll
        for (int r = 0; r < 16; ++r) { accA[r] = 0.f; accB[r] = 0.f; }

        if (wid < 2) {
            if (s < T_LEN) {
                #pragma unroll
                for (int i = 0; i < 12; ++i) {
                    int ks = wid * 12 + i;
                    short8 ah = *(const short8*)(smem_b + AHI_OFF + ks * 1024 + lane * 16);
                    short8 al = *(const short8*)(smem_b + ALO_OFF + ks * 1024 + lane * 16);
                    if (i & 1) {
                        accB = __builtin_amdgcn_mfma_f32_32x32x16_bf16(ah, BH[i], accB, 0, 0, 0);
                        accB = __builtin_amdgcn_mfma_f32_32x32x16_bf16(ah, BL[i], accB, 0, 0, 0);
                        accB = __builtin_amdgcn_mfma_f32_32x32x16_bf16(al, BH[i], accB, 0, 0, 0);
                    } else {
                        accA = __builtin_amdgcn_mfma_f32_32x32x16_bf16(ah, BH[i], accA, 0, 0, 0);
                        accA = __builtin_amdgcn_mfma_f32_32x32x16_bf16(ah, BL[i], accA, 0, 0, 0);
                        accA = __builtin_amdgcn_mfma_f32_32x32x16_bf16(al, BH[i], accA, 0, 0, 0);
                    }
                }
            }
        } else {
            if (s >= 1) {
                #pragma unroll
                for (int i = 0; i < 16; ++i) {
                    int ks = 8 + (wid - 2) * 16 + i;
                    short8 ah = *(const short8*)(smem_b + AHI_OFF + ks * 1024 + lane * 16);
                    short8 al = *(const short8*)(smem_b + ALO_OFF + ks * 1024 + lane * 16);
                    if (i & 1) {
                        accB = __builtin_amdgcn_mfma_f32_32x32x16_bf16(ah, BH[i], accB, 0, 0, 0);
                        accB = __builtin_amdgcn_mfma_f32_32x32x16_bf16(ah, BL[i], accB, 0, 0, 0);
                        accB = __builtin_amdgcn_mfma_f32_32x32x16_bf16(al, BH[i], accB, 0, 0, 0);
                    } else {
                        accA = __builtin_amdgcn_mfma_f32_32x32x16_bf16(ah, BH[i], accA, 0, 0, 0);
                        accA = __builtin_amdgcn_mfma_f32_32x32x16_bf16(ah, BL[i], accA, 0, 0, 0);
                        accA = __builtin_amdgcn_mfma_f32_32x32x16_bf16(al, BH[i], accA, 0, 0, 0);
                    }
                }
            }
        }
        // write partial C -> cred[wid] ([32 n][33 b] f32)
        {
            float* credw = (float*)(smem_b + CRED_OFF) + wid * 1056;
            #pragma unroll
            for (int r = 0; r < 16; ++r) {
                int b = (r & 3) + 8 * (r >> 2) + 4 * half;
                credw[nrow * 33 + b] = accA[r] + accB[r];
            }
        }
        __syncthreads();

        // ================= nonlinearity phase (all 256 threads) =================
        const float* cr = (const float*)(smem_b + CRED_OFF);
        #define CRD(w, g) cr[(w) * 1056 + (jj * 4 + (g)) * 33 + bb]
        if (s < T_LEN) {
            float gi = CRD(0, 0) + CRD(1, 0) + bi_;
            float gf = CRD(0, 1) + CRD(1, 1) + bf_;
            float gg = CRD(0, 2) + CRD(1, 2) + bg_;
            float go = CRD(0, 3) + CRD(1, 3) + bo_;
            float ig = sigmoidf_(gi), fg = sigmoidf_(gf);
            float cg = tanhf_fast(gg), og = sigmoidf_(go);
            c_reg = c_reg * fg + ig * cg;
            float h1v = og * tanhf_fast(c_reg);
            unsigned short h, l;
            split2(h1v, h, l);
            *(unsigned short*)(smem_b + HSTG_OFF + bb * 16 + jj * 2) = h;
            *(unsigned short*)(smem_b + HSTG_OFF + 512 + bb * 16 + jj * 2) = l;
        }
        if (s >= 1) {
            float rc = CRD(2, 0) + CRD(3, 0) + brz_r;
            float zc = CRD(2, 1) + CRD(3, 1) + brz_z;
            float xn = CRD(2, 2) + CRD(3, 2) + bnx_;
            float hn = CRD(2, 3) + CRD(3, 3) + bnh_;
            float rg = sigmoidf_(rc), zg = sigmoidf_(zc);
            float ng = tanhf_fast(xn + rg * hn);
            h2_reg = zg * h2_reg + (1.f - zg) * ng;
            if (s == T_LEN) {
                h2out[(size_t)(grp * 32 + bb) * H_DIM + cu * 8 + jj] = h2_reg;
            } else {
                unsigned short h, l;
                split2(h2_reg, h, l);
                *(unsigned short*)(smem_b + HSTG_OFF + 1024 + bb * 16 + jj * 2) = h;
                *(unsigned short*)(smem_b + HSTG_OFF + 1536 + bb * 16 + jj * 2) = l;
            }
        }
        #undef CRD
        __syncthreads();

        if (s == T_LEN) break;

        // ================= exchange-out (1 u64 atomic store / thread) ==========
        unsigned long long* exg = hxg + (size_t)((s & 1) * 8 + grp) * 8192;
        {
            unsigned long long v = *(const unsigned long long*)
                (smem_b + HSTG_OFF + (tid >> 6) * 512 + (tid & 63) * 8);
            int blk = tid >> 6;
            unsigned long long* dst = exg + ((blk & 1) << 12) + ((blk >> 1) << 11)
                                          + cu * 64 + (tid & 63);
            __hip_atomic_store(dst, v, __ATOMIC_RELAXED, __HIP_MEMORY_SCOPE_AGENT);
        }
        __syncthreads();   // drains every wave's vmcnt before the flag
        if (tid == 0)
            __hip_atomic_store(&flags[(flagBase + cu) * 32], s + 1,
                               __ATOMIC_RELAXED, __HIP_MEMORY_SCOPE_AGENT);
        // prefetch + stage x(s+1) while waiting (slices 0..7 idle now)
        if (s + 1 < T_LEN)
            stage_x_fn(x, smem_b, b0, dir ? (T_LEN - 2 - s) : (s + 1), tid);
        // ---------------- wait on padded per-CU flags --------------------------
        {
            int target = s + 1;
            if (tid < 64) {
                while (true) {
                    int v = (tid < 32)
                        ? __hip_atomic_load(&flags[(flagBase + tid) * 32],
                                            __ATOMIC_RELAXED, __HIP_MEMORY_SCOPE_AGENT)
                        : 0x7fffffff;
                    if (__all(v >= target)) break;
                    __builtin_amdgcn_s_sleep(1);
                }
            }
            __syncthreads();
        }
        // ================= exchange-in: linear copy into A-staging 8..39 =======
        #pragma unroll 8
        for (int i = 0; i < 32; ++i) {
            int f = i * 256 + tid;
            unsigned long long v = __hip_atomic_load(&exg[f], __ATOMIC_RELAXED,
                                                     __HIP_MEMORY_SCOPE_AGENT);
            char* dstb = smem_b + ((f >> 12) ? ALO_OFF : AHI_OFF) + 8192
                       + (size_t)(f & 4095) * 8;
            *(unsigned long long*)dstb = v;
        }
        __syncthreads();
    }
}

// out[b][o] = concat(h_fwd[b], h_bwd[b]) . wo[o] + bo[o]
__global__ __launch_bounds__(128)
void brnn_out(const float* __restrict__ h2out, const float* __restrict__ wo,
              const float* __restrict__ bo, float* __restrict__ out)
{
    __shared__ float hc[512];
    int b = blockIdx.x;
    int o = threadIdx.x;
    int btile = b >> 5, bi = b & 31;
    for (int k = threadIdx.x; k < 256; k += 128) {
        hc[k]       = h2out[((size_t)(btile)     * 32 + bi) * H_DIM + k];
        hc[256 + k] = h2out[((size_t)(4 + btile) * 32 + bi) * H_DIM + k];
    }
    __syncthreads();
    float acc = bo[o];
    const float4* w4 = (const float4*)&wo[(size_t)o * 512];
    #pragma unroll 8
    for (int k = 0; k < 128; ++k) {
        float4 w = w4[k];
        acc += w.x * hc[k * 4] + w.y * hc[k * 4 + 1] + w.z * hc[k * 4 + 2] + w.w * hc[k * 4 + 3];
    }
    out[b * 128 + o] = acc;
}

extern "C" void kernel_launch(void* const* d_in, const int* in_sizes, int n_in,
                              void* d_out, int out_size, void* d_ws, size_t ws_size,
                              hipStream_t stream) {
    const float* x   = (const float*)d_in[0];
    const float* w1x = (const float*)d_in[1];
    const float* b1x = (const float*)d_in[2];
    const float* w1h = (const float*)d_in[3];
    const float* b1h = (const float*)d_in[4];
    const float* w2x = (const float*)d_in[5];
    const float* b2x = (const float*)d_in[6];
    const float* w2h = (const float*)d_in[7];
    const float* b2h = (const float*)d_in[8];
    const float* wo  = (const float*)d_in[9];
    const float* bo  = (const float*)d_in[10];
    float* out = (float*)d_out;

    char* ws = (char*)d_ws;
    int* flags = (int*)ws;                                        // 8*32 padded: 32KB
    unsigned long long* hxg = (unsigned long long*)(ws + 32768);  // 2*8*8192 u64 = 1MB
    float* h2out = (float*)(ws + 32768 + 1048576);                // 256*256 f32 = 256KB

    hipMemsetAsync(flags, 0, 8 * 32 * 32 * sizeof(int), stream);

    size_t shmem = LDS_BYTES;
    hipFuncSetAttribute((const void*)brnn_persistent,
                        hipFuncAttributeMaxDynamicSharedMemorySize, (int)shmem);

    void* args[] = { (void*)&x, (void*)&w1x, (void*)&b1x, (void*)&w1h, (void*)&b1h,
                     (void*)&w2x, (void*)&b2x, (void*)&w2h, (void*)&b2h,
                     (void*)&flags, (void*)&hxg, (void*)&h2out };
    hipError_t err = hipLaunchCooperativeKernel((void*)brnn_persistent,
                                                dim3(256), dim3(256), args,
                                                (unsigned int)shmem, stream);
    if (err != hipSuccess) {
        brnn_persistent<<<dim3(256), dim3(256), shmem, stream>>>(
            x, w1x, b1x, w1h, b1h, w2x, b2x, w2h, b2h, flags, hxg, h2out);
    }

    brnn_out<<<dim3(128), dim3(128), 0, stream>>>(h2out, wo, bo, out);
}